// Round 3
// baseline (25072.821 us; speedup 1.0000x reference)
//
#include <hip/hip_runtime.h>
#include <math.h>

// LSTMEncoder: B=64,S=512,F=128,D=512,U=1024
// gx = x @ (dense_W@Wx) + (dense_b@Wx + b) hoisted out of the scan (chunked).
// Sequential part per step: z = gx_t + h_prev @ Wh; gates i,f,g,o; c,h update.

#define BB 64
#define SS 512
#define FF 128
#define DD 512
#define UU 1024
#define GG 4096  // 4*U
#define CH 32    // timesteps per gx chunk

__device__ __forceinline__ float sigmoidf_(float v) {
    return 1.0f / (1.0f + __expf(-v));
}
__device__ __forceinline__ float tanhf_(float v) {
    float e = __expf(2.0f * v);          // inf-safe: 1 - 2/(e+1)
    return 1.0f - 2.0f / (e + 1.0f);
}

// Wf[f][g] = sum_d dense_W[f][d] * Wx[d][g]
__global__ __launch_bounds__(256) void fuse_w(const float* __restrict__ dW,
                                              const float* __restrict__ Wx,
                                              float* __restrict__ Wf) {
    int tid = blockIdx.x * 256 + threadIdx.x;   // 128*4096 threads
    int g = tid & (GG - 1);
    int f = tid >> 12;
    const float* wr = dW + f * DD;
    float acc = 0.0f;
#pragma unroll 4
    for (int d = 0; d < DD; ++d)
        acc = fmaf(wr[d], Wx[(size_t)d * GG + g], acc);
    Wf[(size_t)f * GG + g] = acc;
}

// bf[g] = sum_d dense_b[d] * Wx[d][g] + b[g]
__global__ __launch_bounds__(256) void fuse_b(const float* __restrict__ db,
                                              const float* __restrict__ Wx,
                                              const float* __restrict__ bias,
                                              float* __restrict__ bf) {
    int g = blockIdx.x * 256 + threadIdx.x;     // 4096
    float acc = bias[g];
#pragma unroll 4
    for (int d = 0; d < DD; ++d)
        acc = fmaf(db[d], Wx[(size_t)d * GG + g], acc);
    bf[g] = acc;
}

// gx chunk: for s in [s0, s0+CH), compute gxc[sl][g][b] = bf[g] + sum_k x[b][s][k]*Wf[k][g]
// Grid: 16 gtiles(256 g) x CH sl = 512 blocks x 512 thr (8 waves, wave = 32 g-cols).
// lane = b; x staged in LDS with +1 pad (bank-free); weights wave-uniform (broadcast).
__global__ __launch_bounds__(512) void gx_chunk(const float* __restrict__ x,
                                                const float* __restrict__ Wf,
                                                const float* __restrict__ bf,
                                                float* __restrict__ gxc, int s0) {
    __shared__ float xs[64 * 129];   // 33KB, pad 129 -> (b+k)%32 banks, conflict-free
    const int sl = blockIdx.x & (CH - 1);
    const int gt = blockIdx.x / CH;          // 0..15
    const int s  = s0 + sl;

    for (int i = threadIdx.x; i < 64 * 128; i += 512) {
        int bb = i >> 7, kk = i & 127;
        xs[bb * 129 + kk] = x[((size_t)bb * SS + s) * FF + kk];
    }
    __syncthreads();

    const int wid = threadIdx.x >> 6;
    const int b   = threadIdx.x & 63;
    const int g0  = __builtin_amdgcn_readfirstlane(gt * 256 + wid * 32);

    float acc[32];
#pragma unroll
    for (int i = 0; i < 32; ++i) acc[i] = bf[g0 + i];

    const float* wp = Wf + g0;
    const float* xp = xs + b * 129;
#pragma unroll 4
    for (int k = 0; k < FF; ++k) {
        float xv = xp[k];
#pragma unroll
        for (int i = 0; i < 32; i += 4) {
            float4 w = *(const float4*)(wp + i);
            acc[i + 0] = fmaf(w.x, xv, acc[i + 0]);
            acc[i + 1] = fmaf(w.y, xv, acc[i + 1]);
            acc[i + 2] = fmaf(w.z, xv, acc[i + 2]);
            acc[i + 3] = fmaf(w.w, xv, acc[i + 3]);
        }
        wp += GG;
    }
    float* op = gxc + ((size_t)sl * GG + g0) * 64 + b;
#pragma unroll
    for (int i = 0; i < 32; ++i) op[i * 64] = acc[i];
}

// One timestep: 256 blocks x 1024 thr (16 waves). Block owns 4 u-cols (16 g-cols).
// Wave = K-slice of 64 k's; lane = b. Weights wave-uniform; h coalesced from hT[k][b].
// Partials reduced through LDS zl[wave][g16][b] (write+read conflict-free).
__global__ __launch_bounds__(1024) void lstm_step(const float* __restrict__ Wh,
                                                  const float* __restrict__ gxc,
                                                  float* __restrict__ out,
                                                  float* __restrict__ cbuf,   // [u][b]
                                                  const float* __restrict__ hprev, // [k][b]
                                                  float* __restrict__ hnext,       // [u][b]
                                                  int t, int tc) {
    __shared__ float zl[16 * 16 * 64];   // 64KB
    const int u0  = blockIdx.x << 2;     // 4 u-cols
    const int wid = threadIdx.x >> 6;    // 0..15
    const int b   = threadIdx.x & 63;

    float acc[16];
#pragma unroll
    for (int i = 0; i < 16; ++i) acc[i] = 0.0f;

    if (t > 0) {
        const int k0 = __builtin_amdgcn_readfirstlane(wid << 6);
        const float* hp = hprev + (size_t)k0 * 64 + b;
        const float* wp = Wh + (size_t)k0 * GG + u0;
#pragma unroll 4
        for (int k = 0; k < 64; ++k) {
            float hv = hp[0];
#pragma unroll
            for (int g = 0; g < 4; ++g) {
                float4 w = *(const float4*)(wp + g * UU);
                acc[g * 4 + 0] = fmaf(w.x, hv, acc[g * 4 + 0]);
                acc[g * 4 + 1] = fmaf(w.y, hv, acc[g * 4 + 1]);
                acc[g * 4 + 2] = fmaf(w.z, hv, acc[g * 4 + 2]);
                acc[g * 4 + 3] = fmaf(w.w, hv, acc[g * 4 + 3]);
            }
            hp += 64;
            wp += GG;
        }
    }
#pragma unroll
    for (int i = 0; i < 16; ++i) zl[wid * 1024 + i * 64 + b] = acc[i];
    __syncthreads();

    if (threadIdx.x < 256) {
        const int rb = threadIdx.x & 63;
        const int j  = threadIdx.x >> 6;     // u_l 0..3
        float z[4];
#pragma unroll
        for (int g = 0; g < 4; ++g) {
            float s = gxc[((size_t)tc * GG + g * UU + u0 + j) * 64 + rb];
#pragma unroll
            for (int w = 0; w < 16; ++w) s += zl[w * 1024 + (g * 4 + j) * 64 + rb];
            z[g] = s;
        }
        float iv = sigmoidf_(z[0]);
        float fv = sigmoidf_(z[1]);
        float gv = tanhf_(z[2]);
        float ov = sigmoidf_(z[3]);

        float* cp = cbuf + (u0 + j) * 64 + rb;
        float cv = fv * (*cp) + iv * gv;
        *cp = cv;
        float hv = ov * tanhf_(cv);

        out[((size_t)rb * SS + t) * UU + u0 + j] = hv;
        hnext[(u0 + j) * 64 + rb] = hv;
    }
}

extern "C" void kernel_launch(void* const* d_in, const int* in_sizes, int n_in,
                              void* d_out, int out_size, void* d_ws, size_t ws_size,
                              hipStream_t stream) {
    const float* x    = (const float*)d_in[0];   // [64,512,128]
    const float* dW   = (const float*)d_in[1];   // [128,512]
    const float* db   = (const float*)d_in[2];   // [512]
    const float* Wx   = (const float*)d_in[3];   // [512,4096]
    const float* Wh   = (const float*)d_in[4];   // [1024,4096]
    const float* bias = (const float*)d_in[5];   // [4096]
    float* out = (float*)d_out;                  // [64,512,1024]

    char* ws = (char*)d_ws;
    size_t off = 0;
    float* Wf   = (float*)(ws + off); off += (size_t)FF * GG * 4;      // 2 MB
    float* bf   = (float*)(ws + off); off += (size_t)GG * 4;           // 16 KB
    float* cbuf = (float*)(ws + off); off += (size_t)BB * UU * 4;      // 256 KB [u][b]
    float* hT0  = (float*)(ws + off); off += (size_t)BB * UU * 4;      // 256 KB [u][b]
    float* hT1  = (float*)(ws + off); off += (size_t)BB * UU * 4;      // 256 KB
    float* gxc  = (float*)(ws + off);                                  // 32 MB [CH][4096][64]

    hipMemsetAsync(cbuf, 0, (size_t)BB * UU * 4, stream);
    fuse_w<<<(FF * GG) / 256, 256, 0, stream>>>(dW, Wx, Wf);
    fuse_b<<<GG / 256, 256, 0, stream>>>(db, Wx, bias, bf);

    float* bufs[2] = {hT0, hT1};
    for (int c = 0; c < SS / CH; ++c) {
        gx_chunk<<<16 * CH, 512, 0, stream>>>(x, Wf, bf, gxc, c * CH);
        for (int tt = 0; tt < CH; ++tt) {
            int t = c * CH + tt;
            lstm_step<<<256, 1024, 0, stream>>>(Wh, gxc, out, cbuf,
                                                bufs[(t + 1) & 1], bufs[t & 1], t, tt);
        }
    }
}

// Round 4
// 10198.656 us; speedup vs baseline: 2.4584x; 2.4584x over previous
//
#include <hip/hip_runtime.h>
#include <math.h>

// LSTMEncoder: B=64,S=512,F=128,D=512,U=1024
// gx = x @ (dense_W@Wx) + (dense_b@Wx + b) hoisted out of the scan (chunked).
// Step: z = gx_t + h_prev @ Wh; gates i,f,g,o (Keras); c,h update.
// Step kernel: 256 blocks = 64 utiles(16u) x 16 btiles(16b); 1024 thr = 16 waves
// (4/SIMD), wave = 64-k slice; weight lines fully used (16 consecutive u);
// XCD = blockIdx%8 = utile%8 -> per-XCD Wh slice 2MB, L2-resident.

#define BB 64
#define SS 512
#define FF 128
#define DD 512
#define UU 1024
#define GG 4096  // 4*U
#define CH 32    // timesteps per gx chunk

__device__ __forceinline__ float sigmoidf_(float v) {
    return 1.0f / (1.0f + __expf(-v));
}
__device__ __forceinline__ float tanhf_(float v) {
    float e = __expf(2.0f * v);          // inf-safe: 1 - 2/(e+1)
    return 1.0f - 2.0f / (e + 1.0f);
}

// Wf[f][g] = sum_d dense_W[f][d] * Wx[d][g]
__global__ __launch_bounds__(256) void fuse_w(const float* __restrict__ dW,
                                              const float* __restrict__ Wx,
                                              float* __restrict__ Wf) {
    int tid = blockIdx.x * 256 + threadIdx.x;   // 128*4096 threads
    int g = tid & (GG - 1);
    int f = tid >> 12;
    const float* wr = dW + f * DD;
    float acc = 0.0f;
#pragma unroll 4
    for (int d = 0; d < DD; ++d)
        acc = fmaf(wr[d], Wx[(size_t)d * GG + g], acc);
    Wf[(size_t)f * GG + g] = acc;
}

// bf[g] = sum_d dense_b[d] * Wx[d][g] + b[g]
__global__ __launch_bounds__(256) void fuse_b(const float* __restrict__ db,
                                              const float* __restrict__ Wx,
                                              const float* __restrict__ bias,
                                              float* __restrict__ bf) {
    int g = blockIdx.x * 256 + threadIdx.x;     // 4096
    float acc = bias[g];
#pragma unroll 4
    for (int d = 0; d < DD; ++d)
        acc = fmaf(db[d], Wx[(size_t)d * GG + g], acc);
    bf[g] = acc;
}

// gx chunk: gxc[sl][b][g] = bf[g] + sum_k x[b][s0+sl][k]*Wf[k][g]
// Grid: 16 gtiles(256 g) x CH = 512 blocks x 512 thr (8 waves, wave = 32 g-cols).
__global__ __launch_bounds__(512) void gx_chunk(const float* __restrict__ x,
                                                const float* __restrict__ Wf,
                                                const float* __restrict__ bf,
                                                float* __restrict__ gxc, int s0) {
    __shared__ float xs[64 * 129];   // pad -> conflict-free
    const int sl = blockIdx.x & (CH - 1);
    const int gt = blockIdx.x / CH;          // 0..15
    const int s  = s0 + sl;

    for (int i = threadIdx.x; i < 64 * 128; i += 512) {
        int bb = i >> 7, kk = i & 127;
        xs[bb * 129 + kk] = x[((size_t)bb * SS + s) * FF + kk];
    }
    __syncthreads();

    const int wid = threadIdx.x >> 6;
    const int b   = threadIdx.x & 63;
    const int g0  = __builtin_amdgcn_readfirstlane(gt * 256 + wid * 32);

    float acc[32];
#pragma unroll
    for (int i = 0; i < 32; ++i) acc[i] = bf[g0 + i];

    const float* wp = Wf + g0;
    const float* xp = xs + b * 129;
#pragma unroll 4
    for (int k = 0; k < FF; ++k) {
        float xv = xp[k];
#pragma unroll
        for (int i = 0; i < 32; i += 4) {
            float4 w = *(const float4*)(wp + i);
            acc[i + 0] = fmaf(w.x, xv, acc[i + 0]);
            acc[i + 1] = fmaf(w.y, xv, acc[i + 1]);
            acc[i + 2] = fmaf(w.z, xv, acc[i + 2]);
            acc[i + 3] = fmaf(w.w, xv, acc[i + 3]);
        }
        wp += GG;
    }
    float* op = gxc + ((size_t)sl * 64 + b) * GG + g0;
#pragma unroll
    for (int i = 0; i < 32; i += 4)
        *(float4*)(op + i) = make_float4(acc[i], acc[i + 1], acc[i + 2], acc[i + 3]);
}

// One timestep.
// Block: utile = blockIdx&63 (u0=utile*16), btile = blockIdx>>6 (16 b).
// 16 waves: wave w = k in [w*64, w*64+64). Lane: u_l=lane&15, bgrp=lane>>4 (4 b each).
// acc[i=b][g]. h from hT[k][64] (float4 per bgrp); weights coalesced over u_l.
__global__ __launch_bounds__(1024, 4) void lstm_step(const float* __restrict__ Wh,
                                                     const float* __restrict__ gxc,
                                                     float* __restrict__ out,
                                                     float* __restrict__ cbuf,       // [u][b]
                                                     const float* __restrict__ hprev, // [k][b]
                                                     float* __restrict__ hnext,       // [u][b]
                                                     int t, int tc) {
    __shared__ float zl[16 * 1024];  // 64KB: [wave][g*256 + u_l*16 + b_l]
    __shared__ float zr[1024];       // 4KB reduced z
    const int utile = blockIdx.x & 63;
    const int btile = blockIdx.x >> 6;
    const int u0 = utile * 16;
    const int wid  = threadIdx.x >> 6;
    const int lane = threadIdx.x & 63;
    const int u_l  = lane & 15;
    const int bgrp = lane >> 4;

    float acc[4][4];   // [b][g]
#pragma unroll
    for (int i = 0; i < 4; ++i)
#pragma unroll
        for (int g = 0; g < 4; ++g) acc[i][g] = 0.0f;

    if (t > 0) {
        const float* hp = hprev + (size_t)(wid * 64) * 64 + btile * 16 + bgrp * 4;
        const float* wp = Wh + (size_t)(wid * 64) * GG + u0 + u_l;
#pragma unroll 4
        for (int k = 0; k < 64; ++k) {
            const float4 h4 = *(const float4*)hp;
            float w0 = wp[0], w1 = wp[UU], w2 = wp[2 * UU], w3 = wp[3 * UU];
            float hv[4] = {h4.x, h4.y, h4.z, h4.w};
#pragma unroll
            for (int i = 0; i < 4; ++i) {
                acc[i][0] = fmaf(hv[i], w0, acc[i][0]);
                acc[i][1] = fmaf(hv[i], w1, acc[i][1]);
                acc[i][2] = fmaf(hv[i], w2, acc[i][2]);
                acc[i][3] = fmaf(hv[i], w3, acc[i][3]);
            }
            hp += 64;
            wp += GG;
        }
    }
    // partials -> LDS (float4 over b within g-group; dense 1KB per (wave,g))
#pragma unroll
    for (int g = 0; g < 4; ++g) {
        *(float4*)&zl[wid * 1024 + g * 256 + u_l * 16 + bgrp * 4] =
            make_float4(acc[0][g], acc[1][g], acc[2][g], acc[3][g]);
    }
    __syncthreads();

    // stage 1: all 1024 threads, 16-way reduce (dense reads)
    {
        float v = 0.0f;
#pragma unroll
        for (int w = 0; w < 16; ++w) v += zl[w * 1024 + threadIdx.x];
        zr[threadIdx.x] = v;
    }
    __syncthreads();

    // stage 2: 256 threads -> one (b,u) each; gates + state update
    if (threadIdx.x < 256) {
        const int b_l  = threadIdx.x >> 4;
        const int u_l2 = threadIdx.x & 15;
        const int bb = btile * 16 + b_l;
        const int uu = u0 + u_l2;

        const float* gp = gxc + ((size_t)tc * 64 + bb) * GG + uu;
        float z[4];
#pragma unroll
        for (int g = 0; g < 4; ++g)
            z[g] = zr[g * 256 + u_l2 * 16 + b_l] + gp[g * UU];

        float iv = sigmoidf_(z[0]);
        float fv = sigmoidf_(z[1]);
        float gv = tanhf_(z[2]);
        float ov = sigmoidf_(z[3]);

        float* cp = cbuf + (size_t)uu * 64 + bb;
        float cv = fv * (*cp) + iv * gv;
        *cp = cv;
        float hv = ov * tanhf_(cv);

        out[((size_t)bb * SS + t) * UU + uu] = hv;
        hnext[(size_t)uu * 64 + bb] = hv;
    }
}

extern "C" void kernel_launch(void* const* d_in, const int* in_sizes, int n_in,
                              void* d_out, int out_size, void* d_ws, size_t ws_size,
                              hipStream_t stream) {
    const float* x    = (const float*)d_in[0];   // [64,512,128]
    const float* dW   = (const float*)d_in[1];   // [128,512]
    const float* db   = (const float*)d_in[2];   // [512]
    const float* Wx   = (const float*)d_in[3];   // [512,4096]
    const float* Wh   = (const float*)d_in[4];   // [1024,4096]
    const float* bias = (const float*)d_in[5];   // [4096]
    float* out = (float*)d_out;                  // [64,512,1024]

    char* ws = (char*)d_ws;
    size_t off = 0;
    float* Wf   = (float*)(ws + off); off += (size_t)FF * GG * 4;      // 2 MB
    float* bf   = (float*)(ws + off); off += (size_t)GG * 4;           // 16 KB
    float* cbuf = (float*)(ws + off); off += (size_t)BB * UU * 4;      // 256 KB [u][b]
    float* hT0  = (float*)(ws + off); off += (size_t)BB * UU * 4;      // 256 KB [k][b]
    float* hT1  = (float*)(ws + off); off += (size_t)BB * UU * 4;      // 256 KB
    float* gxc  = (float*)(ws + off);                                  // 32 MB [CH][64][4096]

    hipMemsetAsync(cbuf, 0, (size_t)BB * UU * 4, stream);
    fuse_w<<<(FF * GG) / 256, 256, 0, stream>>>(dW, Wx, Wf);
    fuse_b<<<GG / 256, 256, 0, stream>>>(db, Wx, bias, bf);

    float* bufs[2] = {hT0, hT1};
    for (int c = 0; c < SS / CH; ++c) {
        gx_chunk<<<16 * CH, 512, 0, stream>>>(x, Wf, bf, gxc, c * CH);
        for (int tt = 0; tt < CH; ++tt) {
            int t = c * CH + tt;
            lstm_step<<<256, 1024, 0, stream>>>(Wh, gxc, out, cbuf,
                                                bufs[(t + 1) & 1], bufs[t & 1], t, tt);
        }
    }
}